// Round 6
// baseline (306.991 us; speedup 1.0000x reference)
//
#include <hip/hip_runtime.h>

#define HW (512 * 512)
#define NBINS 256
#define NB 128
#define NTILES 64          // 8x8 tiles of 64x64
#define TPX 4096           // pixels per tile
#define GB 8               // batches per block in pass

// ---------------- workspace layout (bytes) ----------------
// 0      : tileCount[64]   int
// 512    : counts[256]     int   (per-bin totals, batch-independent)
// 4096   : S1[128][256]    float
// 135168 : S2[128][256]    float
// 266240 : perm[64][4096]  int   packed (bin<<16 | swizzled_slot)

// ---- kernel 1 (once per launch): counting-sort each tile's pixels by bin ----
__global__ __launch_bounds__(256) void tilesort(const int* __restrict__ bins,
                                                int* __restrict__ perm,
                                                int* __restrict__ tileCount,
                                                int* __restrict__ counts) {
    __shared__ int hist[NBINS];
    __shared__ int sc[NBINS];
    __shared__ int cursor[NBINS];
    const int t = threadIdx.x;
    const int tile = blockIdx.x;
    const int trow = tile >> 3, tcol = tile & 7;
    hist[t] = 0;
    __syncthreads();

    int myBins[16];
    #pragma unroll
    for (int k = 0; k < 4; ++k) {
        int row = (t >> 4) + k * 16;
        int col4 = t & 15;
        int4 v = *(const int4*)&bins[(trow * 64 + row) * 512 + tcol * 64 + col4 * 4];
        int bb[4] = {v.x, v.y, v.z, v.w};
        #pragma unroll
        for (int m = 0; m < 4; ++m) {
            myBins[k * 4 + m] = bb[m];
            if (bb[m] > 3 && bb[m] < NBINS) atomicAdd(&hist[bb[m]], 1);
        }
    }
    __syncthreads();
    sc[t] = hist[t];
    __syncthreads();
    for (int off = 1; off < 256; off <<= 1) {
        int x = (t >= off) ? sc[t - off] : 0;
        __syncthreads();
        sc[t] += x;
        __syncthreads();
    }
    cursor[t] = sc[t] - hist[t];     // exclusive prefix
    if (t == 255) tileCount[tile] = sc[255];
    if (hist[t]) atomicAdd(&counts[t], hist[t]);
    __syncthreads();

    #pragma unroll
    for (int k = 0; k < 4; ++k) {
        int row = (t >> 4) + k * 16;
        int col4 = t & 15;
        #pragma unroll
        for (int m = 0; m < 4; ++m) {
            int bn = myBins[k * 4 + m];
            if (bn > 3 && bn < NBINS) {
                int col = col4 * 4 + m;
                int slot = row * 64 + (col ^ (row & 31));   // pre-swizzled LDS slot
                int pos = atomicAdd(&cursor[bn], 1);
                perm[tile * TPX + pos] = (bn << 16) | slot;
            }
        }
    }
}

// ---- kernel 2: main pass — (tile, 8-batch group) per block, pipelined ----
__global__ __launch_bounds__(256, 4) void pass(const float* __restrict__ parts,
                                               const float* __restrict__ projs,
                                               const int* __restrict__ perm,
                                               const int* __restrict__ tileCount,
                                               float* __restrict__ S1,
                                               float* __restrict__ S2) {
    __shared__ float sP[TPX], sQ[TPX];
    __shared__ float h1[NBINS], h2[NBINS];
    const int t = threadIdx.x;
    const int tile = blockIdx.x;
    const int bg = blockIdx.y * GB;
    const int trow = tile >> 3, tcol = tile & 7;
    h1[t] = 0.f; h2[t] = 0.f;

    // ---- decode perm ONCE into registers; sentinel e=-1 for tail ----
    const int count = tileCount[tile];
    const int e0 = t * 16;
    int e[16];
    {
        const int4* pe = (const int4*)(perm + tile * TPX + e0);
        #pragma unroll
        for (int g4 = 0; g4 < 4; ++g4) {
            int4 e4 = pe[g4];
            e[g4 * 4 + 0] = (e0 + g4 * 4 + 0 < count) ? e4.x : -1;
            e[g4 * 4 + 1] = (e0 + g4 * 4 + 1 < count) ? e4.y : -1;
            e[g4 * 4 + 2] = (e0 + g4 * 4 + 2 < count) ? e4.z : -1;
            e[g4 * 4 + 3] = (e0 + g4 * 4 + 3 < count) ? e4.w : -1;
        }
    }

    // staging geometry: thread t covers rows (t>>4)+16k, col group (t&15)*4
    const int row0 = t >> 4;
    const int cb = (t & 15) * 4;
    const int gbase = (trow * 64 + row0) * 512 + tcol * 64 + cb;

    // preload batch bg
    float4 Pr[4], Qr[4];
    {
        const float* Pb = parts + (size_t)bg * HW;
        const float* Qb = projs + (size_t)bg * HW;
        #pragma unroll
        for (int k = 0; k < 4; ++k) {
            Pr[k] = *(const float4*)(Pb + gbase + k * 16 * 512);
            Qr[k] = *(const float4*)(Qb + gbase + k * 16 * 512);
        }
    }

    for (int g = 0; g < GB; ++g) {
        __syncthreads();   // prev gather done; hist (re)zeroed
        // stage current batch to LDS (swizzled scalar writes)
        #pragma unroll
        for (int k = 0; k < 4; ++k) {
            int row = row0 + 16 * k;
            int x = row & 31;
            int rb = row * 64;
            sP[rb + ((cb + 0) ^ x)] = Pr[k].x;
            sP[rb + ((cb + 1) ^ x)] = Pr[k].y;
            sP[rb + ((cb + 2) ^ x)] = Pr[k].z;
            sP[rb + ((cb + 3) ^ x)] = Pr[k].w;
            sQ[rb + ((cb + 0) ^ x)] = Qr[k].x;
            sQ[rb + ((cb + 1) ^ x)] = Qr[k].y;
            sQ[rb + ((cb + 2) ^ x)] = Qr[k].z;
            sQ[rb + ((cb + 3) ^ x)] = Qr[k].w;
        }
        // prefetch next batch while gather runs
        if (g + 1 < GB) {
            const float* Pn = parts + (size_t)(bg + g + 1) * HW;
            const float* Qn = projs + (size_t)(bg + g + 1) * HW;
            #pragma unroll
            for (int k = 0; k < 4; ++k) {
                Pr[k] = *(const float4*)(Pn + gbase + k * 16 * 512);
                Qr[k] = *(const float4*)(Qn + gbase + k * 16 * 512);
            }
        }
        __syncthreads();   // staging visible

        // gather in bin-sorted order, register run-merge
        float a1 = 0.f, a2 = 0.f;
        int curBin = -1;
        #pragma unroll
        for (int k = 0; k < 16; ++k) {
            int bn = e[k] >> 16;            // -1 for sentinel
            if (bn >= 0) {
                int slot = e[k] & 0xFFF;
                float n = sP[slot] - sQ[slot];
                if (bn != curBin) {
                    if (curBin >= 0) {
                        unsafeAtomicAdd(&h1[curBin], a1);
                        unsafeAtomicAdd(&h2[curBin], a2);
                    }
                    curBin = bn; a1 = 0.f; a2 = 0.f;
                }
                a1 += fabsf(n);
                a2 += n * n;
            }
        }
        if (curBin >= 0) {
            unsafeAtomicAdd(&h1[curBin], a1);
            unsafeAtomicAdd(&h2[curBin], a2);
        }
        __syncthreads();   // hist complete

        const int b = bg + g;
        float v1 = h1[t], v2 = h2[t];
        if (v1 != 0.f) unsafeAtomicAdd(&S1[b * NBINS + t], v1);
        if (v2 != 0.f) unsafeAtomicAdd(&S2[b * NBINS + t], v2);
        h1[t] = 0.f; h2[t] = 0.f;
    }
}

// ---- finalize: per-batch closed-form sum over bins ----
__global__ __launch_bounds__(256) void finalize(const float* __restrict__ S1,
                                                const float* __restrict__ S2,
                                                const int* __restrict__ counts,
                                                float* __restrict__ out) {
    const int b = blockIdx.x;
    const int t = threadIdx.x;
    float contrib = 0.f;
    if (t > 3) {   // valid bins 4..255
        float c = (float)counts[t];
        float s1 = S1[b * NBINS + t];
        float s2 = S2[b * NBINS + t];
        float mean = s1 / fmaxf(c, 1.f);
        float ssq = fmaxf(s2 - mean * s1, 0.f);          // = sum (a - mean)^2
        float var = ssq / fmaxf(c - 1.f, 1.f);
        contrib = -0.5f * s2 / var - c * logf(6.283185307179586f * var);
    }
    #pragma unroll
    for (int off = 32; off > 0; off >>= 1) contrib += __shfl_down(contrib, off, 64);
    __shared__ float w[4];
    if ((t & 63) == 0) w[t >> 6] = contrib;
    __syncthreads();
    if (t == 0) out[b] = w[0] + w[1] + w[2] + w[3];
}

extern "C" void kernel_launch(void* const* d_in, const int* in_sizes, int n_in,
                              void* d_out, int out_size, void* d_ws, size_t ws_size,
                              hipStream_t stream) {
    const float* parts = (const float*)d_in[0];
    const float* projs = (const float*)d_in[1];
    const int* bins    = (const int*)d_in[2];
    float* out = (float*)d_out;

    char* ws = (char*)d_ws;
    int*   tileCount = (int*)(ws + 0);
    int*   counts    = (int*)(ws + 512);
    float* S1        = (float*)(ws + 4096);
    float* S2        = (float*)(ws + 135168);
    int*   perm      = (int*)(ws + 266240);

    hipMemsetAsync(d_ws, 0, 266240, stream);   // counts + S1 + S2

    tilesort<<<NTILES, 256, 0, stream>>>(bins, perm, tileCount, counts);
    pass    <<<dim3(NTILES, NB / GB), 256, 0, stream>>>(parts, projs, perm, tileCount, S1, S2);
    finalize<<<NB, 256, 0, stream>>>(S1, S2, counts, out);
}